// Round 2
// baseline (783.913 us; speedup 1.0000x reference)
//
#include <hip/hip_runtime.h>
#include <hip/hip_bf16.h>
#include <math.h>
#include <stdint.h>

typedef __attribute__((ext_vector_type(4))) float floatx4;
typedef __attribute__((ext_vector_type(8))) short shortx8;
typedef __attribute__((ext_vector_type(8))) unsigned short ushortx8;
typedef __attribute__((ext_vector_type(4))) unsigned short ushortx4;

#define BS_CAND 4096   // B*S
#define HDIM    1024
#define MSLOTS  8192
#define THRESH  64.0f

__device__ __forceinline__ unsigned short f2b_bits(float f) {
    __hip_bfloat16 b = __float2bfloat16(f);
    return *(unsigned short*)&b;
}
__device__ __forceinline__ float b2f_bits(unsigned short u) {
    return __uint_as_float(((unsigned)u) << 16);
}

// ---------------- reduction helpers (blockDim == 256) ----------------
__device__ __forceinline__ float blockReduceSum(float x) {
    __shared__ float red[4];
    #pragma unroll
    for (int o = 32; o > 0; o >>= 1) x += __shfl_down(x, o, 64);
    int lane = threadIdx.x & 63, w = threadIdx.x >> 6;
    if (lane == 0) red[w] = x;
    __syncthreads();
    float s = red[0] + red[1] + red[2] + red[3];
    __syncthreads();
    return s;
}

__device__ __forceinline__ float blockReduceMax(float x) {
    __shared__ float redm[4];
    #pragma unroll
    for (int o = 32; o > 0; o >>= 1) x = fmaxf(x, __shfl_down(x, o, 64));
    int lane = threadIdx.x & 63, w = threadIdx.x >> 6;
    if (lane == 0) redm[w] = x;
    __syncthreads();
    float s = fmaxf(fmaxf(redm[0], redm[1]), fmaxf(redm[2], redm[3]));
    __syncthreads();
    return s;
}

// ---------------- surprise = 2*||row||_2 ----------------
__global__ __launch_bounds__(256) void surprise_k(const float* __restrict__ h,
                                                  float* __restrict__ sur) {
    int row = blockIdx.x;
    const float* p = h + (size_t)row * HDIM;
    float s = 0.f;
    for (int i = threadIdx.x; i < HDIM; i += 256) { float v = p[i]; s += v * v; }
    float tot = blockReduceSum(s);
    if (threadIdx.x == 0) sur[row] = 2.0f * sqrtf(tot);
}

// ---------------- rank candidates by surprise, descending, stable -------------
__global__ __launch_bounds__(256) void rank_cand_k(const float* __restrict__ sur,
                                                   int* __restrict__ order) {
    int i = blockIdx.x * 256 + threadIdx.x;   // i < BS_CAND
    float ki = sur[i];
    int r = 0;
    __shared__ float tile[256];
    for (int base = 0; base < BS_CAND; base += 256) {
        __syncthreads();
        tile[threadIdx.x] = sur[base + threadIdx.x];
        __syncthreads();
        #pragma unroll 8
        for (int j = 0; j < 256; j++) {
            float kj = tile[j];
            int jj = base + j;
            r += (kj > ki) || (kj == ki && jj < i);
        }
    }
    order[r] = i;
}

// ---------------- rank slots by importance+noise*1e-6, ascending, stable ------
// also initializes row_src[m] = -1
__global__ __launch_bounds__(256) void rank_slot_k(const float* __restrict__ imp,
                                                   const float* __restrict__ noi,
                                                   int* __restrict__ order,
                                                   int* __restrict__ row_src) {
    int i = blockIdx.x * 256 + threadIdx.x;   // i < MSLOTS
    row_src[i] = -1;
    float ki = imp[i] + noi[i] * 1e-6f;
    int r = 0;
    __shared__ float tile[256];
    for (int base = 0; base < MSLOTS; base += 256) {
        __syncthreads();
        tile[threadIdx.x] = imp[base + threadIdx.x] + noi[base + threadIdx.x] * 1e-6f;
        __syncthreads();
        #pragma unroll 8
        for (int j = 0; j < 256; j++) {
            float kj = tile[j];
            int jj = base + j;
            r += (kj < ki) || (kj == ki && jj < i);
        }
    }
    order[r] = i;
}

// ---------------- scatter: rank-i candidate -> rank-i least-important slot ----
__global__ __launch_bounds__(256) void scatter_k(const int* __restrict__ cand_order,
                                                 const int* __restrict__ slot_order,
                                                 const float* __restrict__ sur,
                                                 int* __restrict__ row_src) {
    int i = blockIdx.x * 256 + threadIdx.x;   // i < BS_CAND
    int c = cand_order[i];
    if (sur[c] > THRESH) row_src[slot_order[i]] = c;
}

// ---------------- fp32 -> bf16 flat convert, 4 elems/thread ----------------
__global__ __launch_bounds__(256) void f2b_k(const float* __restrict__ in,
                                             __hip_bfloat16* __restrict__ out, int n4) {
    int i = blockIdx.x * 256 + threadIdx.x;
    if (i < n4) {
        float4 v = ((const float4*)in)[i];
        ushortx4 o;
        o.x = f2b_bits(v.x); o.y = f2b_bits(v.y);
        o.z = f2b_bits(v.z); o.w = f2b_bits(v.w);
        ((ushortx4*)out)[i] = o;
    }
}

// ---------------- build updated buffer (bf16), 4 elems/thread -------------
__global__ __launch_bounds__(256) void build_b_k(const float* __restrict__ mem,
                                                 const float* __restrict__ hid,
                                                 const int* __restrict__ src,
                                                 __hip_bfloat16* __restrict__ B) {
    int m = blockIdx.x;
    int s = src[m];
    const float4* r = (const float4*)((s < 0) ? (mem + (size_t)m * HDIM)
                                              : (hid + (size_t)s * HDIM));
    float4 v = r[threadIdx.x];                 // HDIM/4 == 256 == blockDim
    ushortx4 o;
    o.x = f2b_bits(v.x); o.y = f2b_bits(v.y);
    o.z = f2b_bits(v.z); o.w = f2b_bits(v.w);
    ((ushortx4*)(B + (size_t)m * HDIM))[threadIdx.x] = o;
}

// ---------------- bf16 transpose [R][C] -> [C][R] ----------------
__global__ __launch_bounds__(256) void transpose_k(const __hip_bfloat16* __restrict__ in,
                                                   __hip_bfloat16* __restrict__ out,
                                                   int R, int C) {
    __shared__ __hip_bfloat16 t[64][65];
    int cb = blockIdx.x * 64, rb = blockIdx.y * 64;
    int tx = threadIdx.x & 63, ty = threadIdx.x >> 6;
    #pragma unroll
    for (int k = 0; k < 16; k++) {
        int r = ty * 16 + k;
        t[r][tx] = in[(size_t)(rb + r) * C + cb + tx];
    }
    __syncthreads();
    #pragma unroll
    for (int k = 0; k < 16; k++) {
        int c = ty * 16 + k;
        out[(size_t)(cb + c) * R + rb + tx] = t[tx][c];
    }
}

// ---------------- async global->LDS helper ----------------
__device__ __forceinline__ void load_lds16(const __hip_bfloat16* g, __hip_bfloat16* l) {
    __builtin_amdgcn_global_load_lds(
        (const __attribute__((address_space(1))) void*)g,
        (__attribute__((address_space(3))) void*)l, 16, 0, 0);
}

// ---------------- BT-GEMM: C[M,N] = A[M,K] * Bt[N,K]^T  (m97 structure) ----------
// EPI 0: outF[idx] = acc * scale               (fp32 out)
// EPI 1: outH[idx] = bf16(acc + bias[col])     (bf16 out)
// EPI 2: outH[idx] = bf16(acc * scale)         (bf16 out)
template <int EPI>
__global__ __launch_bounds__(256) void gemm_bt(const __hip_bfloat16* __restrict__ A,
                                               const __hip_bfloat16* __restrict__ Bt,
                                               float* __restrict__ outF,
                                               __hip_bfloat16* __restrict__ outH,
                                               const float* __restrict__ bias,
                                               int M, int N, int K, float scale) {
    __shared__ alignas(16) __hip_bfloat16 Asm[128 * 64];
    __shared__ alignas(16) __hip_bfloat16 Bsm[128 * 64];
    const int tid = threadIdx.x;
    const int wave = tid >> 6, lane = tid & 63;
    const int bm = blockIdx.y, bn = blockIdx.x;
    const int wr = (wave >> 1) * 64, wc = (wave & 1) * 64;
    const int lm = lane & 15, lq = lane >> 4;

    floatx4 acc[4][4];
    #pragma unroll
    for (int i = 0; i < 4; i++)
        #pragma unroll
        for (int j = 0; j < 4; j++) acc[i][j] = {0.f, 0.f, 0.f, 0.f};

    const __hip_bfloat16* Abase = A + (size_t)bm * 128 * K;
    const __hip_bfloat16* Bbase = Bt + (size_t)bn * 128 * K;

    for (int k0 = 0; k0 < K; k0 += 64) {
        #pragma unroll
        for (int t = 0; t < 4; t++) {
            int c = (wave * 4 + t) * 64 + lane;       // 16B chunk index
            int row = c >> 3, col = (c & 7) * 8;
            load_lds16(Abase + (size_t)row * K + k0 + col, &Asm[(wave * 4 + t) * 512]);
        }
        #pragma unroll
        for (int t = 0; t < 4; t++) {
            int c = (wave * 4 + t) * 64 + lane;
            int row = c >> 3, col = (c & 7) * 8;
            load_lds16(Bbase + (size_t)row * K + k0 + col, &Bsm[(wave * 4 + t) * 512]);
        }
        __syncthreads();
        #pragma unroll
        for (int ks = 0; ks < 2; ks++) {
            shortx8 af[4], bfr[4];
            #pragma unroll
            for (int i = 0; i < 4; i++)
                af[i] = *(const shortx8*)(&Asm[(wr + i * 16 + lm) * 64 + ks * 32 + lq * 8]);
            #pragma unroll
            for (int j = 0; j < 4; j++)
                bfr[j] = *(const shortx8*)(&Bsm[(wc + j * 16 + lm) * 64 + ks * 32 + lq * 8]);
            #pragma unroll
            for (int i = 0; i < 4; i++)
                #pragma unroll
                for (int j = 0; j < 4; j++)
                    acc[i][j] = __builtin_amdgcn_mfma_f32_16x16x32_bf16(af[i], bfr[j],
                                                                        acc[i][j], 0, 0, 0);
        }
        __syncthreads();
    }

    #pragma unroll
    for (int i = 0; i < 4; i++) {
        int grow0 = bm * 128 + wr + i * 16 + lq * 4;
        #pragma unroll
        for (int j = 0; j < 4; j++) {
            int gcol = bn * 128 + wc + j * 16 + lm;
            #pragma unroll
            for (int r = 0; r < 4; r++) {
                float v = acc[i][j][r];
                size_t idx = (size_t)(grow0 + r) * N + gcol;
                if (EPI == 0)      outF[idx] = v * scale;
                else if (EPI == 1) outH[idx] = __float2bfloat16(v + bias[gcol]);
                else               outH[idx] = __float2bfloat16(v * scale);
            }
        }
    }
}

// ---------------- in-place row softmax on bf16 S[4096][8192] ----------------
__global__ __launch_bounds__(256) void softmax_bf_k(__hip_bfloat16* __restrict__ S) {
    int row = blockIdx.x;
    ushortx8* sp = (ushortx8*)(S + (size_t)row * MSLOTS);
    float v[32];
    float mx = -3.0e38f;
    #pragma unroll
    for (int c = 0; c < 4; c++) {
        ushortx8 x = sp[threadIdx.x + c * 256];
        #pragma unroll
        for (int e = 0; e < 8; e++) {
            float f = b2f_bits(x[e]);
            v[c * 8 + e] = f;
            mx = fmaxf(mx, f);
        }
    }
    mx = blockReduceMax(mx);
    float sum = 0.f;
    #pragma unroll
    for (int i = 0; i < 32; i++) { v[i] = __expf(v[i] - mx); sum += v[i]; }
    sum = blockReduceSum(sum);
    float inv = 1.f / sum;
    #pragma unroll
    for (int c = 0; c < 4; c++) {
        ushortx8 x;
        #pragma unroll
        for (int e = 0; e < 8; e++) x[e] = f2b_bits(v[c * 8 + e] * inv);
        sp[threadIdx.x + c * 256] = x;
    }
}

// ---------------- launch ----------------
extern "C" void kernel_launch(void* const* d_in, const int* in_sizes, int n_in,
                              void* d_out, int out_size, void* d_ws, size_t ws_size,
                              hipStream_t stream) {
    const float* hidden = (const float*)d_in[0];   // [2,2048,1024]
    const float* membuf = (const float*)d_in[1];   // [8192,1024]
    const float* imp    = (const float*)d_in[2];   // [8192]
    const float* Wq     = (const float*)d_in[3];   // [1024,1024]
    const float* bq     = (const float*)d_in[4];   // [1024]
    const float* Wk     = (const float*)d_in[5];   // [1024,1024]
    const float* bk     = (const float*)d_in[6];   // [1024]
    const float* noise  = (const float*)d_in[7];   // [8192]

    char* ws = (char*)d_ws;
    size_t off = 0;
    auto alloc = [&](size_t bytes) -> void* {
        void* p = ws + off;
        off += (bytes + 255) & ~(size_t)255;
        return p;
    };
    // --- persistent-ish region (front) ---
    float*          surprise = (float*)alloc(BS_CAND * 4);
    int*            cand_ord = (int*)alloc(BS_CAND * 4);
    int*            slot_ord = (int*)alloc(MSLOTS * 4);
    int*            row_src  = (int*)alloc(MSLOTS * 4);
    __hip_bfloat16* Wqbf = (__hip_bfloat16*)alloc((size_t)HDIM * HDIM * 2);    // 2 MB
    __hip_bfloat16* Wkbf = (__hip_bfloat16*)alloc((size_t)HDIM * HDIM * 2);    // 2 MB
    __hip_bfloat16* qbf  = (__hip_bfloat16*)alloc((size_t)BS_CAND * HDIM * 2); // 8 MB
    __hip_bfloat16* mkbf = (__hip_bfloat16*)alloc((size_t)MSLOTS * HDIM * 2);  // 16 MB
    __hip_bfloat16* BbfT = (__hip_bfloat16*)alloc((size_t)HDIM * MSLOTS * 2);  // 16 MB
    // --- overlay region: Sbf (64 MB) over Hbf (8 MB) + Bbf (16 MB), which are
    // dead before the scores GEMM first writes Sbf ---
    size_t s_base = off;
    __hip_bfloat16* Sbf = (__hip_bfloat16*)(ws + s_base);                      // 64 MB
    __hip_bfloat16* Hbf = (__hip_bfloat16*)(ws + s_base);                      //  8 MB
    __hip_bfloat16* Bbf = (__hip_bfloat16*)(ws + s_base + (size_t)BS_CAND * HDIM * 2);
    // peak usage = s_base + 64 MB  (~108 MB total)

    // 1) selection phase
    surprise_k<<<BS_CAND, 256, 0, stream>>>(hidden, surprise);
    rank_cand_k<<<BS_CAND / 256, 256, 0, stream>>>(surprise, cand_ord);
    rank_slot_k<<<MSLOTS / 256, 256, 0, stream>>>(imp, noise, slot_ord, row_src);
    scatter_k<<<BS_CAND / 256, 256, 0, stream>>>(cand_ord, slot_ord, surprise, row_src);

    // 2) bf16 materialization
    f2b_k<<<(BS_CAND * HDIM / 4) / 256, 256, 0, stream>>>(hidden, Hbf, BS_CAND * HDIM / 4);
    f2b_k<<<(HDIM * HDIM / 4) / 256, 256, 0, stream>>>(Wq, Wqbf, HDIM * HDIM / 4);
    f2b_k<<<(HDIM * HDIM / 4) / 256, 256, 0, stream>>>(Wk, Wkbf, HDIM * HDIM / 4);
    build_b_k<<<MSLOTS, 256, 0, stream>>>(membuf, hidden, row_src, Bbf);
    transpose_k<<<dim3(HDIM / 64, MSLOTS / 64), 256, 0, stream>>>(Bbf, BbfT, MSLOTS, HDIM);

    // 3) q = hidden @ Wq^T + bq   -> bf16 [4096,1024]   (Hbf dies after this)
    gemm_bt<1><<<dim3(HDIM / 128, BS_CAND / 128), 256, 0, stream>>>(
        Hbf, Wqbf, nullptr, qbf, bq, BS_CAND, HDIM, HDIM, 1.f);
    // 4) mk = newbuf @ Wk^T + bk  -> bf16 [8192,1024]   (Bbf dies after this)
    gemm_bt<1><<<dim3(HDIM / 128, MSLOTS / 128), 256, 0, stream>>>(
        Bbf, Wkbf, nullptr, mkbf, bk, MSLOTS, HDIM, HDIM, 1.f);
    // 5) S = bf16((q @ mk^T) / 32)  [4096,8192] — overwrites Hbf/Bbf region
    gemm_bt<2><<<dim3(MSLOTS / 128, BS_CAND / 128), 256, 0, stream>>>(
        qbf, mkbf, nullptr, Sbf, nullptr, BS_CAND, MSLOTS, HDIM, 0.03125f);
    // 6) P = softmax(S) in place   -> bf16 [4096,8192]
    softmax_bf_k<<<BS_CAND, 256, 0, stream>>>(Sbf);
    // 7) out = P @ newbuf          -> fp32 [4096,1024]
    gemm_bt<0><<<dim3(HDIM / 128, BS_CAND / 128), 256, 0, stream>>>(
        Sbf, BbfT, (float*)d_out, nullptr, nullptr, BS_CAND, HDIM, MSLOTS, 1.f);
}

// Round 3
// 506.233 us; speedup vs baseline: 1.5485x; 1.5485x over previous
//
#include <hip/hip_runtime.h>
#include <hip/hip_bf16.h>
#include <math.h>
#include <stdint.h>

typedef __attribute__((ext_vector_type(4))) float floatx4;
typedef __attribute__((ext_vector_type(8))) short shortx8;
typedef __attribute__((ext_vector_type(8))) unsigned short ushortx8;
typedef __attribute__((ext_vector_type(4))) unsigned short ushortx4;

#define BS_CAND 4096   // B*S
#define HDIM    1024
#define MSLOTS  8192
#define THRESH  64.0f

__device__ __forceinline__ unsigned short f2b_bits(float f) {
    __hip_bfloat16 b = __float2bfloat16(f);
    return *(unsigned short*)&b;
}
__device__ __forceinline__ float b2f_bits(unsigned short u) {
    return __uint_as_float(((unsigned)u) << 16);
}

// ---------------- reduction helpers (blockDim == 256) ----------------
__device__ __forceinline__ float blockReduceSum(float x) {
    __shared__ float red[4];
    #pragma unroll
    for (int o = 32; o > 0; o >>= 1) x += __shfl_down(x, o, 64);
    int lane = threadIdx.x & 63, w = threadIdx.x >> 6;
    if (lane == 0) red[w] = x;
    __syncthreads();
    float s = red[0] + red[1] + red[2] + red[3];
    __syncthreads();
    return s;
}

__device__ __forceinline__ float blockReduceMax(float x) {
    __shared__ float redm[4];
    #pragma unroll
    for (int o = 32; o > 0; o >>= 1) x = fmaxf(x, __shfl_down(x, o, 64));
    int lane = threadIdx.x & 63, w = threadIdx.x >> 6;
    if (lane == 0) redm[w] = x;
    __syncthreads();
    float s = fmaxf(fmaxf(redm[0], redm[1]), fmaxf(redm[2], redm[3]));
    __syncthreads();
    return s;
}

// ---------------- surprise = 2*||row||_2 ----------------
__global__ __launch_bounds__(256) void surprise_k(const float* __restrict__ h,
                                                  float* __restrict__ sur) {
    int row = blockIdx.x;
    const float* p = h + (size_t)row * HDIM;
    float s = 0.f;
    for (int i = threadIdx.x; i < HDIM; i += 256) { float v = p[i]; s += v * v; }
    float tot = blockReduceSum(s);
    if (threadIdx.x == 0) sur[row] = 2.0f * sqrtf(tot);
}

// ---------------- slot keys = imp + 1e-6*noise; row_src = -1 ----------------
__global__ __launch_bounds__(256) void slot_keys_k(const float* __restrict__ imp,
                                                   const float* __restrict__ noi,
                                                   float* __restrict__ keys,
                                                   int* __restrict__ row_src) {
    int i = blockIdx.x * 256 + threadIdx.x;
    keys[i] = imp[i] + noi[i] * 1e-6f;
    row_src[i] = -1;
}

// ---------------- rank by counting: one BLOCK per element ----------------
// DESC=1: rank among descending order; DESC=0: ascending. Stable (ties by index).
template <int DESC>
__global__ __launch_bounds__(256) void rank_k(const float* __restrict__ keys,
                                              int n, int* __restrict__ order) {
    int i = blockIdx.x;
    float ki = keys[i];
    float cnt = 0.f;
    for (int j = threadIdx.x; j < n; j += 256) {
        float kj = keys[j];
        bool before = DESC ? (kj > ki) : (kj < ki);
        cnt += (before || (kj == ki && j < i)) ? 1.f : 0.f;
    }
    float r = blockReduceSum(cnt);
    if (threadIdx.x == 0) order[(int)r] = i;
}

// ---------------- scatter: rank-i candidate -> rank-i least-important slot ----
__global__ __launch_bounds__(256) void scatter_k(const int* __restrict__ cand_order,
                                                 const int* __restrict__ slot_order,
                                                 const float* __restrict__ sur,
                                                 int* __restrict__ row_src) {
    int i = blockIdx.x * 256 + threadIdx.x;   // i < BS_CAND
    int c = cand_order[i];
    if (sur[c] > THRESH) row_src[slot_order[i]] = c;
}

// ---------------- fp32 -> bf16 flat convert, 4 elems/thread ----------------
__global__ __launch_bounds__(256) void f2b_k(const float* __restrict__ in,
                                             __hip_bfloat16* __restrict__ out, int n4) {
    int i = blockIdx.x * 256 + threadIdx.x;
    if (i < n4) {
        float4 v = ((const float4*)in)[i];
        ushortx4 o;
        o.x = f2b_bits(v.x); o.y = f2b_bits(v.y);
        o.z = f2b_bits(v.z); o.w = f2b_bits(v.w);
        ((ushortx4*)out)[i] = o;
    }
}

// ---------------- build updated buffer (bf16), 4 elems/thread -------------
__global__ __launch_bounds__(256) void build_b_k(const float* __restrict__ mem,
                                                 const float* __restrict__ hid,
                                                 const int* __restrict__ src,
                                                 __hip_bfloat16* __restrict__ B) {
    int m = blockIdx.x;
    int s = src[m];
    const float4* r = (const float4*)((s < 0) ? (mem + (size_t)m * HDIM)
                                              : (hid + (size_t)s * HDIM));
    float4 v = r[threadIdx.x];                 // HDIM/4 == 256 == blockDim
    ushortx4 o;
    o.x = f2b_bits(v.x); o.y = f2b_bits(v.y);
    o.z = f2b_bits(v.z); o.w = f2b_bits(v.w);
    ((ushortx4*)(B + (size_t)m * HDIM))[threadIdx.x] = o;
}

// ---------------- bf16 transpose [R][C] -> [C][R] ----------------
__global__ __launch_bounds__(256) void transpose_k(const __hip_bfloat16* __restrict__ in,
                                                   __hip_bfloat16* __restrict__ out,
                                                   int R, int C) {
    __shared__ __hip_bfloat16 t[64][65];
    int cb = blockIdx.x * 64, rb = blockIdx.y * 64;
    int tx = threadIdx.x & 63, ty = threadIdx.x >> 6;
    #pragma unroll
    for (int k = 0; k < 16; k++) {
        int r = ty * 16 + k;
        t[r][tx] = in[(size_t)(rb + r) * C + cb + tx];
    }
    __syncthreads();
    #pragma unroll
    for (int k = 0; k < 16; k++) {
        int c = ty * 16 + k;
        out[(size_t)(cb + c) * R + rb + tx] = t[tx][c];
    }
}

// ---------------- async global->LDS helper ----------------
__device__ __forceinline__ void load_lds16(const __hip_bfloat16* g, __hip_bfloat16* l) {
    __builtin_amdgcn_global_load_lds(
        (const __attribute__((address_space(1))) void*)g,
        (__attribute__((address_space(3))) void*)l, 16, 0, 0);
}

// ---------------- BT-GEMM: C[M,N] = A[M,K] * Bt[N,K]^T  (m97 structure) ----------
// EPI 0: outF[idx] = acc * scale               (fp32 out)
// EPI 1: outH[idx] = bf16(acc + bias[col])     (bf16 out)
// EPI 2: outH[idx] = bf16(acc * scale)         (bf16 out)
template <int EPI>
__global__ __launch_bounds__(256) void gemm_bt(const __hip_bfloat16* __restrict__ A,
                                               const __hip_bfloat16* __restrict__ Bt,
                                               float* __restrict__ outF,
                                               __hip_bfloat16* __restrict__ outH,
                                               const float* __restrict__ bias,
                                               int M, int N, int K, float scale) {
    __shared__ alignas(16) __hip_bfloat16 Asm[128 * 64];
    __shared__ alignas(16) __hip_bfloat16 Bsm[128 * 64];
    const int tid = threadIdx.x;
    const int wave = tid >> 6, lane = tid & 63;
    const int bm = blockIdx.y, bn = blockIdx.x;
    const int wr = (wave >> 1) * 64, wc = (wave & 1) * 64;
    const int lm = lane & 15, lq = lane >> 4;

    floatx4 acc[4][4];
    #pragma unroll
    for (int i = 0; i < 4; i++)
        #pragma unroll
        for (int j = 0; j < 4; j++) acc[i][j] = {0.f, 0.f, 0.f, 0.f};

    const __hip_bfloat16* Abase = A + (size_t)bm * 128 * K;
    const __hip_bfloat16* Bbase = Bt + (size_t)bn * 128 * K;

    for (int k0 = 0; k0 < K; k0 += 64) {
        #pragma unroll
        for (int t = 0; t < 4; t++) {
            int c = (wave * 4 + t) * 64 + lane;       // 16B chunk index
            int row = c >> 3, col = (c & 7) * 8;
            load_lds16(Abase + (size_t)row * K + k0 + col, &Asm[(wave * 4 + t) * 512]);
        }
        #pragma unroll
        for (int t = 0; t < 4; t++) {
            int c = (wave * 4 + t) * 64 + lane;
            int row = c >> 3, col = (c & 7) * 8;
            load_lds16(Bbase + (size_t)row * K + k0 + col, &Bsm[(wave * 4 + t) * 512]);
        }
        __syncthreads();
        #pragma unroll
        for (int ks = 0; ks < 2; ks++) {
            shortx8 af[4], bfr[4];
            #pragma unroll
            for (int i = 0; i < 4; i++)
                af[i] = *(const shortx8*)(&Asm[(wr + i * 16 + lm) * 64 + ks * 32 + lq * 8]);
            #pragma unroll
            for (int j = 0; j < 4; j++)
                bfr[j] = *(const shortx8*)(&Bsm[(wc + j * 16 + lm) * 64 + ks * 32 + lq * 8]);
            #pragma unroll
            for (int i = 0; i < 4; i++)
                #pragma unroll
                for (int j = 0; j < 4; j++)
                    acc[i][j] = __builtin_amdgcn_mfma_f32_16x16x32_bf16(af[i], bfr[j],
                                                                        acc[i][j], 0, 0, 0);
        }
        __syncthreads();
    }

    #pragma unroll
    for (int i = 0; i < 4; i++) {
        int grow0 = bm * 128 + wr + i * 16 + lq * 4;
        #pragma unroll
        for (int j = 0; j < 4; j++) {
            int gcol = bn * 128 + wc + j * 16 + lm;
            #pragma unroll
            for (int r = 0; r < 4; r++) {
                float v = acc[i][j][r];
                size_t idx = (size_t)(grow0 + r) * N + gcol;
                if (EPI == 0)      outF[idx] = v * scale;
                else if (EPI == 1) outH[idx] = __float2bfloat16(v + bias[gcol]);
                else               outH[idx] = __float2bfloat16(v * scale);
            }
        }
    }
}

// ---------------- in-place row softmax on bf16 S[4096][8192] ----------------
__global__ __launch_bounds__(256) void softmax_bf_k(__hip_bfloat16* __restrict__ S) {
    int row = blockIdx.x;
    ushortx8* sp = (ushortx8*)(S + (size_t)row * MSLOTS);
    float v[32];
    float mx = -3.0e38f;
    #pragma unroll
    for (int c = 0; c < 4; c++) {
        ushortx8 x = sp[threadIdx.x + c * 256];
        #pragma unroll
        for (int e = 0; e < 8; e++) {
            float f = b2f_bits(x[e]);
            v[c * 8 + e] = f;
            mx = fmaxf(mx, f);
        }
    }
    mx = blockReduceMax(mx);
    float sum = 0.f;
    #pragma unroll
    for (int i = 0; i < 32; i++) { v[i] = __expf(v[i] - mx); sum += v[i]; }
    sum = blockReduceSum(sum);
    float inv = 1.f / sum;
    #pragma unroll
    for (int c = 0; c < 4; c++) {
        ushortx8 x;
        #pragma unroll
        for (int e = 0; e < 8; e++) x[e] = f2b_bits(v[c * 8 + e] * inv);
        sp[threadIdx.x + c * 256] = x;
    }
}

// ---------------- launch ----------------
extern "C" void kernel_launch(void* const* d_in, const int* in_sizes, int n_in,
                              void* d_out, int out_size, void* d_ws, size_t ws_size,
                              hipStream_t stream) {
    const float* hidden = (const float*)d_in[0];   // [2,2048,1024]
    const float* membuf = (const float*)d_in[1];   // [8192,1024]
    const float* imp    = (const float*)d_in[2];   // [8192]
    const float* Wq     = (const float*)d_in[3];   // [1024,1024]
    const float* bq     = (const float*)d_in[4];   // [1024]
    const float* Wk     = (const float*)d_in[5];   // [1024,1024]
    const float* bk     = (const float*)d_in[6];   // [1024]
    const float* noise  = (const float*)d_in[7];   // [8192]

    char* ws = (char*)d_ws;
    size_t off = 0;
    auto alloc = [&](size_t bytes) -> void* {
        void* p = ws + off;
        off += (bytes + 255) & ~(size_t)255;
        return p;
    };
    // --- persistent-ish region (front) ---
    float*          surprise = (float*)alloc(BS_CAND * 4);
    float*          skeys    = (float*)alloc(MSLOTS * 4);
    int*            cand_ord = (int*)alloc(BS_CAND * 4);
    int*            slot_ord = (int*)alloc(MSLOTS * 4);
    int*            row_src  = (int*)alloc(MSLOTS * 4);
    __hip_bfloat16* Wqbf = (__hip_bfloat16*)alloc((size_t)HDIM * HDIM * 2);    // 2 MB
    __hip_bfloat16* Wkbf = (__hip_bfloat16*)alloc((size_t)HDIM * HDIM * 2);    // 2 MB
    __hip_bfloat16* qbf  = (__hip_bfloat16*)alloc((size_t)BS_CAND * HDIM * 2); // 8 MB
    __hip_bfloat16* mkbf = (__hip_bfloat16*)alloc((size_t)MSLOTS * HDIM * 2);  // 16 MB
    __hip_bfloat16* BbfT = (__hip_bfloat16*)alloc((size_t)HDIM * MSLOTS * 2);  // 16 MB
    // --- overlay region: Sbf (64 MB) over Hbf (8 MB) + Bbf (16 MB), which are
    // dead before the scores GEMM first writes Sbf ---
    size_t s_base = off;
    __hip_bfloat16* Sbf = (__hip_bfloat16*)(ws + s_base);                      // 64 MB
    __hip_bfloat16* Hbf = (__hip_bfloat16*)(ws + s_base);                      //  8 MB
    __hip_bfloat16* Bbf = (__hip_bfloat16*)(ws + s_base + (size_t)BS_CAND * HDIM * 2);
    // peak usage = s_base + 64 MB  (~108 MB total)

    // 1) selection phase
    surprise_k<<<BS_CAND, 256, 0, stream>>>(hidden, surprise);
    slot_keys_k<<<MSLOTS / 256, 256, 0, stream>>>(imp, noise, skeys, row_src);
    rank_k<1><<<BS_CAND, 256, 0, stream>>>(surprise, BS_CAND, cand_ord);
    rank_k<0><<<MSLOTS, 256, 0, stream>>>(skeys, MSLOTS, slot_ord);
    scatter_k<<<BS_CAND / 256, 256, 0, stream>>>(cand_ord, slot_ord, surprise, row_src);

    // 2) bf16 materialization
    f2b_k<<<(BS_CAND * HDIM / 4) / 256, 256, 0, stream>>>(hidden, Hbf, BS_CAND * HDIM / 4);
    f2b_k<<<(HDIM * HDIM / 4) / 256, 256, 0, stream>>>(Wq, Wqbf, HDIM * HDIM / 4);
    f2b_k<<<(HDIM * HDIM / 4) / 256, 256, 0, stream>>>(Wk, Wkbf, HDIM * HDIM / 4);
    build_b_k<<<MSLOTS, 256, 0, stream>>>(membuf, hidden, row_src, Bbf);
    transpose_k<<<dim3(HDIM / 64, MSLOTS / 64), 256, 0, stream>>>(Bbf, BbfT, MSLOTS, HDIM);

    // 3) q = hidden @ Wq^T + bq   -> bf16 [4096,1024]   (Hbf dies after this)
    gemm_bt<1><<<dim3(HDIM / 128, BS_CAND / 128), 256, 0, stream>>>(
        Hbf, Wqbf, nullptr, qbf, bq, BS_CAND, HDIM, HDIM, 1.f);
    // 4) mk = newbuf @ Wk^T + bk  -> bf16 [8192,1024]   (Bbf dies after this)
    gemm_bt<1><<<dim3(HDIM / 128, MSLOTS / 128), 256, 0, stream>>>(
        Bbf, Wkbf, nullptr, mkbf, bk, MSLOTS, HDIM, HDIM, 1.f);
    // 5) S = bf16((q @ mk^T) / 32)  [4096,8192] — overwrites Hbf/Bbf region
    gemm_bt<2><<<dim3(MSLOTS / 128, BS_CAND / 128), 256, 0, stream>>>(
        qbf, mkbf, nullptr, Sbf, nullptr, BS_CAND, MSLOTS, HDIM, 0.03125f);
    // 6) P = softmax(S) in place   -> bf16 [4096,8192]
    softmax_bf_k<<<BS_CAND, 256, 0, stream>>>(Sbf);
    // 7) out = P @ newbuf          -> fp32 [4096,1024]
    gemm_bt<0><<<dim3(HDIM / 128, BS_CAND / 128), 256, 0, stream>>>(
        Sbf, BbfT, (float*)d_out, nullptr, nullptr, BS_CAND, HDIM, MSLOTS, 1.f);
}

// Round 4
// 455.823 us; speedup vs baseline: 1.7198x; 1.1106x over previous
//
#include <hip/hip_runtime.h>
#include <hip/hip_bf16.h>
#include <math.h>
#include <stdint.h>

typedef __attribute__((ext_vector_type(4))) float floatx4;
typedef __attribute__((ext_vector_type(8))) short shortx8;
typedef __attribute__((ext_vector_type(8))) unsigned short ushortx8;
typedef __attribute__((ext_vector_type(4))) unsigned short ushortx4;

#define BS_CAND 4096   // B*S
#define HDIM    1024
#define MSLOTS  8192
#define THRESH  64.0f
#define PV_SPLIT 4

__device__ __forceinline__ unsigned short f2b_bits(float f) {
    __hip_bfloat16 b = __float2bfloat16(f);
    return *(unsigned short*)&b;
}
__device__ __forceinline__ float b2f_bits(unsigned short u) {
    return __uint_as_float(((unsigned)u) << 16);
}

// ---------------- reduction helpers (blockDim == 256) ----------------
__device__ __forceinline__ float blockReduceSum(float x) {
    __shared__ float red[4];
    #pragma unroll
    for (int o = 32; o > 0; o >>= 1) x += __shfl_down(x, o, 64);
    int lane = threadIdx.x & 63, w = threadIdx.x >> 6;
    if (lane == 0) red[w] = x;
    __syncthreads();
    float s = red[0] + red[1] + red[2] + red[3];
    __syncthreads();
    return s;
}

__device__ __forceinline__ float blockReduceMax(float x) {
    __shared__ float redm[4];
    #pragma unroll
    for (int o = 32; o > 0; o >>= 1) x = fmaxf(x, __shfl_down(x, o, 64));
    int lane = threadIdx.x & 63, w = threadIdx.x >> 6;
    if (lane == 0) redm[w] = x;
    __syncthreads();
    float s = fmaxf(fmaxf(redm[0], redm[1]), fmaxf(redm[2], redm[3]));
    __syncthreads();
    return s;
}

// ---------------- surprise = 2*||row||_2 ----------------
__global__ __launch_bounds__(256) void surprise_k(const float* __restrict__ h,
                                                  float* __restrict__ sur) {
    int row = blockIdx.x;
    const float* p = h + (size_t)row * HDIM;
    float s = 0.f;
    for (int i = threadIdx.x; i < HDIM; i += 256) { float v = p[i]; s += v * v; }
    float tot = blockReduceSum(s);
    if (threadIdx.x == 0) sur[row] = 2.0f * sqrtf(tot);
}

// ---------------- slot keys = imp + 1e-6*noise; row_src = -1 ----------------
__global__ __launch_bounds__(256) void slot_keys_k(const float* __restrict__ imp,
                                                   const float* __restrict__ noi,
                                                   float* __restrict__ keys,
                                                   int* __restrict__ row_src) {
    int i = blockIdx.x * 256 + threadIdx.x;
    keys[i] = imp[i] + noi[i] * 1e-6f;
    row_src[i] = -1;
}

// ---------------- rank by counting: one BLOCK per element ----------------
// DESC=1: rank among descending order; DESC=0: ascending. Stable (ties by index).
template <int DESC>
__global__ __launch_bounds__(256) void rank_k(const float* __restrict__ keys,
                                              int n, int* __restrict__ order) {
    int i = blockIdx.x;
    float ki = keys[i];
    float cnt = 0.f;
    for (int j = threadIdx.x; j < n; j += 256) {
        float kj = keys[j];
        bool before = DESC ? (kj > ki) : (kj < ki);
        cnt += (before || (kj == ki && j < i)) ? 1.f : 0.f;
    }
    float r = blockReduceSum(cnt);
    if (threadIdx.x == 0) order[(int)r] = i;
}

// ---------------- scatter: rank-i candidate -> rank-i least-important slot ----
__global__ __launch_bounds__(256) void scatter_k(const int* __restrict__ cand_order,
                                                 const int* __restrict__ slot_order,
                                                 const float* __restrict__ sur,
                                                 int* __restrict__ row_src) {
    int i = blockIdx.x * 256 + threadIdx.x;   // i < BS_CAND
    int c = cand_order[i];
    if (sur[c] > THRESH) row_src[slot_order[i]] = c;
}

// ---------------- fp32 -> bf16 flat convert, 4 elems/thread ----------------
__global__ __launch_bounds__(256) void f2b_k(const float* __restrict__ in,
                                             __hip_bfloat16* __restrict__ out, int n4) {
    int i = blockIdx.x * 256 + threadIdx.x;
    if (i < n4) {
        float4 v = ((const float4*)in)[i];
        ushortx4 o;
        o.x = f2b_bits(v.x); o.y = f2b_bits(v.y);
        o.z = f2b_bits(v.z); o.w = f2b_bits(v.w);
        ((ushortx4*)out)[i] = o;
    }
}

// ---------------- build updated buffer (bf16), 4 elems/thread -------------
__global__ __launch_bounds__(256) void build_b_k(const float* __restrict__ mem,
                                                 const float* __restrict__ hid,
                                                 const int* __restrict__ src,
                                                 __hip_bfloat16* __restrict__ B) {
    int m = blockIdx.x;
    int s = src[m];
    const float4* r = (const float4*)((s < 0) ? (mem + (size_t)m * HDIM)
                                              : (hid + (size_t)s * HDIM));
    float4 v = r[threadIdx.x];                 // HDIM/4 == 256 == blockDim
    ushortx4 o;
    o.x = f2b_bits(v.x); o.y = f2b_bits(v.y);
    o.z = f2b_bits(v.z); o.w = f2b_bits(v.w);
    ((ushortx4*)(B + (size_t)m * HDIM))[threadIdx.x] = o;
}

// ---------------- bf16 transpose [R][C] -> [C][R] ----------------
__global__ __launch_bounds__(256) void transpose_k(const __hip_bfloat16* __restrict__ in,
                                                   __hip_bfloat16* __restrict__ out,
                                                   int R, int C) {
    __shared__ __hip_bfloat16 t[64][65];
    int cb = blockIdx.x * 64, rb = blockIdx.y * 64;
    int tx = threadIdx.x & 63, ty = threadIdx.x >> 6;
    #pragma unroll
    for (int k = 0; k < 16; k++) {
        int r = ty * 16 + k;
        t[r][tx] = in[(size_t)(rb + r) * C + cb + tx];
    }
    __syncthreads();
    #pragma unroll
    for (int k = 0; k < 16; k++) {
        int c = ty * 16 + k;
        out[(size_t)(cb + c) * R + rb + tx] = t[tx][c];
    }
}

// ---------------- async global->LDS helper ----------------
__device__ __forceinline__ void load_lds16(const __hip_bfloat16* g, __hip_bfloat16* l) {
    __builtin_amdgcn_global_load_lds(
        (const __attribute__((address_space(1))) void*)g,
        (__attribute__((address_space(3))) void*)l, 16, 0, 0);
}

// ---------------- BT-GEMM: C[M,N] = A[M,K] * Bt[N,K]^T  (m97 structure) ----------
// K-range [kb, ke) over full stride K; split index blockIdx.z offsets output.
// EPI 0: outF[z*M*N + idx] = acc * scale       (fp32 out, split-K partial)
// EPI 1: outH[idx] = bf16(acc + bias[col])     (bf16 out)
// EPI 2: outH[idx] = bf16(acc * scale)         (bf16 out)
template <int EPI>
__global__ __launch_bounds__(256) void gemm_bt(const __hip_bfloat16* __restrict__ A,
                                               const __hip_bfloat16* __restrict__ Bt,
                                               float* __restrict__ outF,
                                               __hip_bfloat16* __restrict__ outH,
                                               const float* __restrict__ bias,
                                               int M, int N, int K, int ksplit,
                                               float scale) {
    __shared__ alignas(16) __hip_bfloat16 Asm[128 * 64];
    __shared__ alignas(16) __hip_bfloat16 Bsm[128 * 64];
    const int tid = threadIdx.x;
    const int wave = tid >> 6, lane = tid & 63;
    const int bm = blockIdx.y, bn = blockIdx.x;
    const int kb = blockIdx.z * ksplit, ke = kb + ksplit;
    const int wr = (wave >> 1) * 64, wc = (wave & 1) * 64;
    const int lm = lane & 15, lq = lane >> 4;

    floatx4 acc[4][4];
    #pragma unroll
    for (int i = 0; i < 4; i++)
        #pragma unroll
        for (int j = 0; j < 4; j++) acc[i][j] = {0.f, 0.f, 0.f, 0.f};

    const __hip_bfloat16* Abase = A + (size_t)bm * 128 * K;
    const __hip_bfloat16* Bbase = Bt + (size_t)bn * 128 * K;

    for (int k0 = kb; k0 < ke; k0 += 64) {
        #pragma unroll
        for (int t = 0; t < 4; t++) {
            int c = (wave * 4 + t) * 64 + lane;       // 16B chunk index
            int row = c >> 3, col = (c & 7) * 8;
            load_lds16(Abase + (size_t)row * K + k0 + col, &Asm[(wave * 4 + t) * 512]);
        }
        #pragma unroll
        for (int t = 0; t < 4; t++) {
            int c = (wave * 4 + t) * 64 + lane;
            int row = c >> 3, col = (c & 7) * 8;
            load_lds16(Bbase + (size_t)row * K + k0 + col, &Bsm[(wave * 4 + t) * 512]);
        }
        __syncthreads();
        #pragma unroll
        for (int ks = 0; ks < 2; ks++) {
            shortx8 af[4], bfr[4];
            #pragma unroll
            for (int i = 0; i < 4; i++)
                af[i] = *(const shortx8*)(&Asm[(wr + i * 16 + lm) * 64 + ks * 32 + lq * 8]);
            #pragma unroll
            for (int j = 0; j < 4; j++)
                bfr[j] = *(const shortx8*)(&Bsm[(wc + j * 16 + lm) * 64 + ks * 32 + lq * 8]);
            #pragma unroll
            for (int i = 0; i < 4; i++)
                #pragma unroll
                for (int j = 0; j < 4; j++)
                    acc[i][j] = __builtin_amdgcn_mfma_f32_16x16x32_bf16(af[i], bfr[j],
                                                                        acc[i][j], 0, 0, 0);
        }
        __syncthreads();
    }

    float* outFz = outF + (size_t)blockIdx.z * M * N;
    #pragma unroll
    for (int i = 0; i < 4; i++) {
        int grow0 = bm * 128 + wr + i * 16 + lq * 4;
        #pragma unroll
        for (int j = 0; j < 4; j++) {
            int gcol = bn * 128 + wc + j * 16 + lm;
            #pragma unroll
            for (int r = 0; r < 4; r++) {
                float v = acc[i][j][r];
                size_t idx = (size_t)(grow0 + r) * N + gcol;
                if (EPI == 0)      outFz[idx] = v * scale;
                else if (EPI == 1) outH[idx] = __float2bfloat16(v + bias[gcol]);
                else               outH[idx] = __float2bfloat16(v * scale);
            }
        }
    }
}

// ---------------- sum 4 fp32 partials -> out ----------------
__global__ __launch_bounds__(256) void reduce4_k(const float4* __restrict__ p,
                                                 float4* __restrict__ out, int n4) {
    int i = blockIdx.x * 256 + threadIdx.x;
    if (i < n4) {
        float4 a = p[i], b = p[i + n4], c = p[i + 2 * n4], d = p[i + 3 * n4];
        float4 o;
        o.x = (a.x + b.x) + (c.x + d.x);
        o.y = (a.y + b.y) + (c.y + d.y);
        o.z = (a.z + b.z) + (c.z + d.z);
        o.w = (a.w + b.w) + (c.w + d.w);
        out[i] = o;
    }
}

// ---------------- in-place row softmax on bf16 S[4096][8192] ----------------
__global__ __launch_bounds__(256) void softmax_bf_k(__hip_bfloat16* __restrict__ S) {
    int row = blockIdx.x;
    ushortx8* sp = (ushortx8*)(S + (size_t)row * MSLOTS);
    float v[32];
    float mx = -3.0e38f;
    #pragma unroll
    for (int c = 0; c < 4; c++) {
        ushortx8 x = sp[threadIdx.x + c * 256];
        #pragma unroll
        for (int e = 0; e < 8; e++) {
            float f = b2f_bits(x[e]);
            v[c * 8 + e] = f;
            mx = fmaxf(mx, f);
        }
    }
    mx = blockReduceMax(mx);
    float sum = 0.f;
    #pragma unroll
    for (int i = 0; i < 32; i++) { v[i] = __expf(v[i] - mx); sum += v[i]; }
    sum = blockReduceSum(sum);
    float inv = 1.f / sum;
    #pragma unroll
    for (int c = 0; c < 4; c++) {
        ushortx8 x;
        #pragma unroll
        for (int e = 0; e < 8; e++) x[e] = f2b_bits(v[c * 8 + e] * inv);
        sp[threadIdx.x + c * 256] = x;
    }
}

// ---------------- launch ----------------
extern "C" void kernel_launch(void* const* d_in, const int* in_sizes, int n_in,
                              void* d_out, int out_size, void* d_ws, size_t ws_size,
                              hipStream_t stream) {
    const float* hidden = (const float*)d_in[0];   // [2,2048,1024]
    const float* membuf = (const float*)d_in[1];   // [8192,1024]
    const float* imp    = (const float*)d_in[2];   // [8192]
    const float* Wq     = (const float*)d_in[3];   // [1024,1024]
    const float* bq     = (const float*)d_in[4];   // [1024]
    const float* Wk     = (const float*)d_in[5];   // [1024,1024]
    const float* bk     = (const float*)d_in[6];   // [1024]
    const float* noise  = (const float*)d_in[7];   // [8192]

    char* ws = (char*)d_ws;
    size_t off = 0;
    auto alloc = [&](size_t bytes) -> void* {
        void* p = ws + off;
        off += (bytes + 255) & ~(size_t)255;
        return p;
    };
    // --- persistent region (front) ---
    float*          surprise = (float*)alloc(BS_CAND * 4);
    float*          skeys    = (float*)alloc(MSLOTS * 4);
    int*            cand_ord = (int*)alloc(BS_CAND * 4);
    int*            slot_ord = (int*)alloc(MSLOTS * 4);
    int*            row_src  = (int*)alloc(MSLOTS * 4);
    __hip_bfloat16* Wqbf = (__hip_bfloat16*)alloc((size_t)HDIM * HDIM * 2);    // 2 MB
    __hip_bfloat16* Wkbf = (__hip_bfloat16*)alloc((size_t)HDIM * HDIM * 2);    // 2 MB
    __hip_bfloat16* BbfT = (__hip_bfloat16*)alloc((size_t)HDIM * MSLOTS * 2);  // 16 MB
    // --- Sbf region (64 MB), overlaid with Hbf (8 MB) + Bbf (16 MB) which die
    // before the scores GEMM writes Sbf ---
    size_t s_base = off;
    __hip_bfloat16* Sbf = (__hip_bfloat16*)(ws + s_base);                      // 64 MB
    __hip_bfloat16* Hbf = (__hip_bfloat16*)(ws + s_base);                      //  8 MB
    __hip_bfloat16* Bbf = (__hip_bfloat16*)(ws + s_base + (size_t)BS_CAND * HDIM * 2);
    off = s_base + ((size_t)BS_CAND * MSLOTS * 2 + 255) & ~(size_t)255;
    // --- tail region: qbf+mkbf live until scores GEMM; PV partials (64 MB)
    // overlay them afterwards ---
    size_t t_base = off;
    __hip_bfloat16* qbf  = (__hip_bfloat16*)alloc((size_t)BS_CAND * HDIM * 2); // 8 MB
    __hip_bfloat16* mkbf = (__hip_bfloat16*)alloc((size_t)MSLOTS * HDIM * 2);  // 16 MB
    float*          part = (float*)(ws + t_base);       // 4 x 16 MB fp32 partials
    // peak usage = t_base + 64 MB  (~148 MB total)

    // 1) selection phase
    surprise_k<<<BS_CAND, 256, 0, stream>>>(hidden, surprise);
    slot_keys_k<<<MSLOTS / 256, 256, 0, stream>>>(imp, noise, skeys, row_src);
    rank_k<1><<<BS_CAND, 256, 0, stream>>>(surprise, BS_CAND, cand_ord);
    rank_k<0><<<MSLOTS, 256, 0, stream>>>(skeys, MSLOTS, slot_ord);
    scatter_k<<<BS_CAND / 256, 256, 0, stream>>>(cand_ord, slot_ord, surprise, row_src);

    // 2) bf16 materialization
    f2b_k<<<(BS_CAND * HDIM / 4) / 256, 256, 0, stream>>>(hidden, Hbf, BS_CAND * HDIM / 4);
    f2b_k<<<(HDIM * HDIM / 4) / 256, 256, 0, stream>>>(Wq, Wqbf, HDIM * HDIM / 4);
    f2b_k<<<(HDIM * HDIM / 4) / 256, 256, 0, stream>>>(Wk, Wkbf, HDIM * HDIM / 4);
    build_b_k<<<MSLOTS, 256, 0, stream>>>(membuf, hidden, row_src, Bbf);
    transpose_k<<<dim3(HDIM / 64, MSLOTS / 64), 256, 0, stream>>>(Bbf, BbfT, MSLOTS, HDIM);

    // 3) q = hidden @ Wq^T + bq   -> bf16 [4096,1024]   (Hbf dies after this)
    gemm_bt<1><<<dim3(HDIM / 128, BS_CAND / 128), 256, 0, stream>>>(
        Hbf, Wqbf, nullptr, qbf, bq, BS_CAND, HDIM, HDIM, HDIM, 1.f);
    // 4) mk = newbuf @ Wk^T + bk  -> bf16 [8192,1024]   (Bbf dies after this)
    gemm_bt<1><<<dim3(HDIM / 128, MSLOTS / 128), 256, 0, stream>>>(
        Bbf, Wkbf, nullptr, mkbf, bk, MSLOTS, HDIM, HDIM, HDIM, 1.f);
    // 5) S = bf16((q @ mk^T) / 32)  [4096,8192] — overwrites Hbf/Bbf region
    gemm_bt<2><<<dim3(MSLOTS / 128, BS_CAND / 128), 256, 0, stream>>>(
        qbf, mkbf, nullptr, Sbf, nullptr, BS_CAND, MSLOTS, HDIM, HDIM, 0.03125f);
    // 6) P = softmax(S) in place   -> bf16 [4096,8192]  (qbf/mkbf die here)
    softmax_bf_k<<<BS_CAND, 256, 0, stream>>>(Sbf);
    // 7) split-K PV: partial[z] = P @ newbuf over K-chunk z  (overlays qbf/mkbf)
    gemm_bt<0><<<dim3(HDIM / 128, BS_CAND / 128, PV_SPLIT), 256, 0, stream>>>(
        Sbf, BbfT, part, nullptr, nullptr, BS_CAND, HDIM, MSLOTS, MSLOTS / PV_SPLIT, 1.f);
    // 8) out = sum of 4 partials   -> fp32 [4096,1024]
    reduce4_k<<<(BS_CAND * HDIM / 4) / 256, 256, 0, stream>>>(
        (const float4*)part, (float4*)d_out, BS_CAND * HDIM / 4);
}